// Round 11
// baseline (400.209 us; speedup 1.0000x reference)
//
#include <hip/hip_runtime.h>

// Problem constants
#define E_ 158
#define F_ 2049
#define T_ 64
#define C_ 2
#define B_ 8
#define EF 323742           // E_*F_
#define EF2 161871          // EF/2 (float2 units per t-chunk)
#define EFT 20719488        // EF*T_ (per-batch element count)
#define NOUT 165755904      // B_*EFT
#define N4B 5179872         // EFT/4 (float4s per batch)
#define NSEG 16
#define SEG2 10117          // ceil(EF2/NSEG); last segment = 10116

// gate config: per-batch grid-stride
#define GBLK 512            // blocks per batch (x-dim)
#define GSTRIDE (GBLK * 256)   // 131072, divisible by 16 -> t invariant/thread

typedef float vfloat4 __attribute__((ext_vector_type(4)));

// ---------------------------------------------------------------------------
// Kernel 1: proj[b,k] = xind[b,0]*W[k,0] + xind[b,1]*W[k,1] + bias[k]
// Written directly into the anchor region of d_out (anchor == proj flat).
// ---------------------------------------------------------------------------
__global__ __launch_bounds__(256) void proj_kernel(
    const float* __restrict__ xind, const float* __restrict__ W,
    const float* __restrict__ bias, float* __restrict__ anchor)
{
    unsigned int idx = blockIdx.x * 256u + threadIdx.x;
    if (idx >= (unsigned int)(B_ * EF)) return;
    unsigned int b = idx / (unsigned int)EF;
    unsigned int k = idx - b * (unsigned int)EF;
    anchor[idx] = xind[b * 2 + 0] * W[2 * k + 0]
                + xind[b * 2 + 1] * W[2 * k + 1]
                + bias[k];
}

// ---------------------------------------------------------------------------
// Kernel 2 (round-7 proven): partial dots. Block (b,t,s) sums an 81KB
// contiguous chunk of xs_flat[b, t*EF + seg_s] against proj[b, seg_s].
// 8192 blocks saturate the HBM read ceiling; same-(b,s) blocks are 16 apart
// -> proj segment re-reads L2-resident.
// ---------------------------------------------------------------------------
__global__ __launch_bounds__(256) void rx_all_kernel(
    const float* __restrict__ xs, const float* __restrict__ proj,
    float* __restrict__ part)
{
    const int blk = blockIdx.x;           // b*1024 + t*16 + s
    const int b = blk >> 10;
    const int t = (blk >> 4) & 63;
    const int s = blk & 15;
    const int len2 = (s == NSEG - 1) ? (EF2 - (NSEG - 1) * SEG2) : SEG2;

    const float2* __restrict__ xp =
        (const float2*)(xs + (size_t)b * EFT) + (size_t)t * EF2 + (size_t)s * SEG2;
    const float2* __restrict__ pp =
        (const float2*)(proj + (size_t)b * EF) + (size_t)s * SEG2;

    float acc = 0.f;
    #pragma unroll 4
    for (int i = threadIdx.x; i < len2; i += 256) {
        float2 x = xp[i];
        float2 p = pp[i];
        acc += x.x * p.x + x.y * p.y;
    }
    #pragma unroll
    for (int off = 32; off > 0; off >>= 1)
        acc += __shfl_down(acc, off, 64);

    __shared__ float sacc[4];
    if ((threadIdx.x & 63) == 0) sacc[threadIdx.x >> 6] = acc;
    __syncthreads();
    if (threadIdx.x == 0)
        part[blk] = sacc[0] + sacc[1] + sacc[2] + sacc[3];
}

// ---------------------------------------------------------------------------
// Kernel 3: gate with fused Rx finalize. Prologue: threads 0..63 reduce the
// 16 partials for their t in FIXED order (identical in every block ->
// deterministic; part[] is L2-resident after the first blocks). Main loop:
// per-batch grid-stride, b = blockIdx.y, t invariant per thread; plain xs
// load (leaves lines cacheable), nontemporal out store (never re-read).
// ---------------------------------------------------------------------------
__global__ __launch_bounds__(256) void gate_all_kernel(
    const float* __restrict__ xs, const float* __restrict__ proj,
    const float* __restrict__ part, float* __restrict__ out)
{
    const int b = blockIdx.y;

    __shared__ float sRx[T_];
    if (threadIdx.x < T_) {
        const float* __restrict__ pt = part + (b * T_ + threadIdx.x) * NSEG;
        float r = 0.f;
        #pragma unroll
        for (int s = 0; s < NSEG; ++s) r += pt[s];
        sRx[threadIdx.x] = r;
    }
    __syncthreads();

    const unsigned base = blockIdx.x * 256u + threadIdx.x;   // [0, GSTRIDE)
    const unsigned t0 = (base & 15u) * 4u;                   // loop-invariant
    const float4 rx4 = *(const float4*)(sRx + t0);
    const float* __restrict__ pj = proj + (size_t)b * EF;
    const vfloat4* __restrict__ xs4 = (const vfloat4*)xs + (size_t)b * N4B;
    vfloat4* __restrict__ out4 = (vfloat4*)out + (size_t)b * N4B;

    #pragma unroll 2
    for (unsigned idx4 = base; idx4 < (unsigned)N4B; idx4 += GSTRIDE) {
        float p = pj[idx4 >> 4];                 // k = idx4/16, L2-resident
        vfloat4 x = xs4[idx4];
        vfloat4 o;
        o.x = x.x * p * rx4.x;
        o.y = x.y * p * rx4.y;
        o.z = x.z * p * rx4.z;
        o.w = x.w * p * rx4.w;
        __builtin_nontemporal_store(o, &out4[idx4]);
    }
}

extern "C" void kernel_launch(void* const* d_in, const int* in_sizes, int n_in,
                              void* d_out, int out_size, void* d_ws, size_t ws_size,
                              hipStream_t stream)
{
    const float* xs   = (const float*)d_in[0];   // [B,E,F,T]
    const float* xind = (const float*)d_in[1];   // [B,C]
    const float* W    = (const float*)d_in[2];   // [E*F, C]
    const float* bias = (const float*)d_in[3];   // [E*F]

    float* out    = (float*)d_out;                    // [B,E,F,T] flat
    float* anchor = (float*)d_out + (size_t)NOUT;     // [B,F,E] flat == proj
    float* part   = (float*)d_ws;                     // [B][64][16] = 8192 f

    // 1) proj -> anchor region (doubles as proj operand)
    {
        const int n = B_ * EF;                        // 2,589,936
        proj_kernel<<<(n + 255) / 256, 256, 0, stream>>>(xind, W, bias, anchor);
    }
    // 2) partial dots: 8192 contiguous-chunk blocks
    rx_all_kernel<<<B_ * T_ * NSEG, 256, 0, stream>>>(xs, anchor, part);
    // 3) gate with fused deterministic Rx finalize
    gate_all_kernel<<<dim3(GBLK, B_), 256, 0, stream>>>(xs, anchor, part, out);
}

// Round 12
// 369.644 us; speedup vs baseline: 1.0827x; 1.0827x over previous
//
#include <hip/hip_runtime.h>

// Problem constants
#define E_ 158
#define F_ 2049
#define T_ 64
#define C_ 2
#define B_ 8
#define EF 323742           // E_*F_
#define EF2 161871          // EF/2 (float2 units per t-chunk)
#define EFT 20719488        // EF*T_ (per-batch element count)
#define NOUT 165755904      // B_*EFT
#define N4TOT 41438976      // NOUT/4 (float4s total); 161871 blocks x 256 exact
#define NSEG 16
#define SEG2 10117          // ceil(EF2/NSEG); last segment = 10116

// ---------------------------------------------------------------------------
// Kernel 1: proj[b,k] = xind[b,0]*W[k,0] + xind[b,1]*W[k,1] + bias[k]
// Written directly into the anchor region of d_out (anchor == proj flat).
// ---------------------------------------------------------------------------
__global__ __launch_bounds__(256) void proj_kernel(
    const float* __restrict__ xind, const float* __restrict__ W,
    const float* __restrict__ bias, float* __restrict__ anchor)
{
    unsigned int idx = blockIdx.x * 256u + threadIdx.x;
    if (idx >= (unsigned int)(B_ * EF)) return;
    unsigned int b = idx / (unsigned int)EF;
    unsigned int k = idx - b * (unsigned int)EF;
    anchor[idx] = xind[b * 2 + 0] * W[2 * k + 0]
                + xind[b * 2 + 1] * W[2 * k + 1]
                + bias[k];
}

// ---------------------------------------------------------------------------
// Kernel 2: partial dots. Block (b,t,s) sums an 81KB contiguous chunk of
// xs_flat[b, t*EF + seg_s] against proj[b, seg_s]. Grid = 8*64*16 = 8192
// blocks -> saturates HBM read ceiling; same-(b,s) blocks 16 apart -> proj
// re-reads L2-resident.
// ---------------------------------------------------------------------------
__global__ __launch_bounds__(256) void rx_all_kernel(
    const float* __restrict__ xs, const float* __restrict__ proj,
    float* __restrict__ part)
{
    const int blk = blockIdx.x;           // b*1024 + t*16 + s
    const int b = blk >> 10;
    const int t = (blk >> 4) & 63;
    const int s = blk & 15;
    const int len2 = (s == NSEG - 1) ? (EF2 - (NSEG - 1) * SEG2) : SEG2;

    const float2* __restrict__ xp =
        (const float2*)(xs + (size_t)b * EFT) + (size_t)t * EF2 + (size_t)s * SEG2;
    const float2* __restrict__ pp =
        (const float2*)(proj + (size_t)b * EF) + (size_t)s * SEG2;

    float acc = 0.f;
    #pragma unroll 4
    for (int i = threadIdx.x; i < len2; i += 256) {
        float2 x = xp[i];
        float2 p = pp[i];
        acc += x.x * p.x + x.y * p.y;
    }
    #pragma unroll
    for (int off = 32; off > 0; off >>= 1)
        acc += __shfl_down(acc, off, 64);

    __shared__ float sacc[4];
    if ((threadIdx.x & 63) == 0) sacc[threadIdx.x >> 6] = acc;
    __syncthreads();
    if (threadIdx.x == 0)
        part[blk] = sacc[0] + sacc[1] + sacc[2] + sacc[3];
}

// ---------------------------------------------------------------------------
// Kernel 3: Rx[bt] = sum_s part[bt*16+s], one block, fixed order -> bitwise
// deterministic across replays.
// ---------------------------------------------------------------------------
__global__ __launch_bounds__(512) void rx_final_kernel(
    const float* __restrict__ part, float* __restrict__ Rx)
{
    const int bt = threadIdx.x;           // b*64 + t
    float r = 0.f;
    #pragma unroll
    for (int s = 0; s < NSEG; ++s) r += part[bt * NSEG + s];
    Rx[bt] = r;
}

// ---------------------------------------------------------------------------
// Kernel 4: out[i = b*EFT + k*T + t] = xs[i] * proj[b,k] * Rx[b,t], float4
// over t. Blocks walk addresses in REVERSE so the first-processed addresses
// are the ones rx_all streamed last (possible L3 lingering; harmless if not).
// ---------------------------------------------------------------------------
__global__ __launch_bounds__(256) void gate_all_kernel(
    const float* __restrict__ xs, const float* __restrict__ proj,
    const float* __restrict__ Rx, float* __restrict__ out)
{
    unsigned int rb = (unsigned int)(gridDim.x - 1u - blockIdx.x);
    unsigned int idx4 = rb * 256u + threadIdx.x;   // [0, N4TOT), exact cover
    unsigned int i = idx4 * 4u;
    unsigned int b = i / (unsigned int)EFT;
    unsigned int r = i - b * (unsigned int)EFT;
    unsigned int k = r >> 6;
    unsigned int t = r & 63u;                      // t % 4 == 0

    float p = proj[(size_t)b * EF + k];
    const float4 rx4 = *(const float4*)(Rx + b * T_ + t);
    float4 x = ((const float4*)xs)[idx4];
    float4 o;
    o.x = x.x * p * rx4.x;
    o.y = x.y * p * rx4.y;
    o.z = x.z * p * rx4.z;
    o.w = x.w * p * rx4.w;
    ((float4*)out)[idx4] = o;
}

extern "C" void kernel_launch(void* const* d_in, const int* in_sizes, int n_in,
                              void* d_out, int out_size, void* d_ws, size_t ws_size,
                              hipStream_t stream)
{
    const float* xs   = (const float*)d_in[0];   // [B,E,F,T]
    const float* xind = (const float*)d_in[1];   // [B,C]
    const float* W    = (const float*)d_in[2];   // [E*F, C]
    const float* bias = (const float*)d_in[3];   // [E*F]

    float* out    = (float*)d_out;                    // [B,E,F,T] flat
    float* anchor = (float*)d_out + (size_t)NOUT;     // [B,F,E] flat == proj
    float* part   = (float*)d_ws;                     // [B][64][16] = 8192 f
    float* Rx     = (float*)d_ws + B_ * T_ * NSEG;    // [B][64] = 512 f (16B-aligned)

    // 1) proj -> anchor region (doubles as proj operand)
    {
        const int n = B_ * EF;                        // 2,589,936
        proj_kernel<<<(n + 255) / 256, 256, 0, stream>>>(xind, W, bias, anchor);
    }
    // 2) partial dots: 8192 blocks, each a contiguous 81KB chunk
    rx_all_kernel<<<B_ * T_ * NSEG, 256, 0, stream>>>(xs, anchor, part);
    // 3) finalize Rx (deterministic fixed-order sum)
    rx_final_kernel<<<1, 512, 0, stream>>>(part, Rx);
    // 4) gate, reverse-order for L3 reuse of rx_all's tail
    gate_all_kernel<<<N4TOT / 256, 256, 0, stream>>>(xs, anchor, Rx, out);
}